// Round 3
// baseline (312.995 us; speedup 1.0000x reference)
//
#include <hip/hip_runtime.h>
#include <hip/hip_bf16.h>

#define N_ROWS 8192
#define DIM 256
#define TAU_INV 2.0f
#define BM 128
#define NTILE 64           // N_ROWS / BM
#define JCHUNK 8           // column tiles walked per block

typedef float f32x4 __attribute__((ext_vector_type(4)));
typedef short bf16x8 __attribute__((ext_vector_type(8)));

// ---------------------------------------------------------------------------
// Kernel 1: L2-normalize rows of z1,z2 -> bf16 An,Bn; fp32 self/cross dots of
// the QUANTIZED values (so they match the MFMA diagonal exactly). Also zeroes
// the 4 S accumulator arrays (32768 floats) so no separate memset node.
// ---------------------------------------------------------------------------
__global__ __launch_bounds__(256) void normalize_kernel(
    const float* __restrict__ z1, const float* __restrict__ z2,
    __hip_bfloat16* __restrict__ An, __hip_bfloat16* __restrict__ Bn,
    float* __restrict__ d_aa, float* __restrict__ d_bb, float* __restrict__ pos,
    float* __restrict__ Szero)
{
    const int row = blockIdx.x;
    const int t = threadIdx.x;            // 0..255 == DIM
    if (row < 128) Szero[row * 256 + t] = 0.0f;   // 128*256 = 32768 = 4*N_ROWS

    const float a = z1[row * DIM + t];
    const float b = z2[row * DIM + t];

    __shared__ float red[4];

    auto blockSum = [&](float v) -> float {
        #pragma unroll
        for (int m = 1; m < 64; m <<= 1) v += __shfl_xor(v, m, 64);
        if ((t & 63) == 0) red[t >> 6] = v;
        __syncthreads();
        float r = red[0] + red[1] + red[2] + red[3];
        __syncthreads();
        return r;
    };

    const float na2 = blockSum(a * a);
    const float nb2 = blockSum(b * b);
    const float inv_a = 1.0f / sqrtf(na2);   // norms ~16; eps never binds
    const float inv_b = 1.0f / sqrtf(nb2);

    const __hip_bfloat16 ah = __float2bfloat16(a * inv_a);
    const __hip_bfloat16 bh = __float2bfloat16(b * inv_b);
    An[row * DIM + t] = ah;
    Bn[row * DIM + t] = bh;

    const float af = __bfloat162float(ah);
    const float bf = __bfloat162float(bh);
    const float qa = blockSum(af * af);
    const float qb = blockSum(bf * bf);
    const float qd = blockSum(af * bf);
    if (t == 0) { d_aa[row] = qa; d_bb[row] = qb; pos[row] = qd; }
}

// ---------------------------------------------------------------------------
// Kernel 2: A-stationary gram. grid = (8 jchunks, 64 itiles, 3 modes).
// Block stages full-K A-tile (128x256 bf16 = 64 KB, 16B-group XOR swizzle)
// into LDS once, then walks JCHUNK column tiles streaming B fragments
// global->registers (prefetch distance 1, NO barriers in the walk).
// exp(2C) epilogue per tile; row sums accumulate in registers across the
// walk (atomics once per block); col sums shuffle-reduced per tile.
// Symmetric modes (AA/BB): upper-triangular tiles only, col sums of
// off-diagonal tiles scatter into the row-sum array.
// ---------------------------------------------------------------------------
__global__ __launch_bounds__(256) void gram_kernel(
    const __hip_bfloat16* __restrict__ An, const __hip_bfloat16* __restrict__ Bn,
    float* __restrict__ S_aa, float* __restrict__ S_bb,
    float* __restrict__ S_abr, float* __restrict__ S_abc)
{
    const int mode = blockIdx.z;
    const int i = blockIdx.y;
    int j0 = blockIdx.x * JCHUNK;
    int j1 = j0 + JCHUNK;

    const __hip_bfloat16 *X, *Y;
    float *Srow, *Scol;
    bool sym;
    if (mode == 0)      { X = An; Y = Bn; Srow = S_abr; Scol = S_abc; sym = false; }
    else if (mode == 1) { X = An; Y = An; Srow = S_aa;  Scol = S_aa;  sym = true; }
    else                { X = Bn; Y = Bn; Srow = S_bb;  Scol = S_bb;  sym = true; }

    if (sym) {
        if (j1 <= i) return;          // chunk entirely below diagonal
        if (j0 < i) j0 = i;
    }

    __shared__ __hip_bfloat16 As[BM * DIM];   // 64 KB

    const int tid  = threadIdx.x;
    const int wave = tid >> 6;
    const int lane = tid & 63;
    const int wr = wave >> 1;     // row half (0..1)
    const int wc = wave & 1;      // col half
    const int lm = lane & 15;
    const int lq = lane >> 4;

    // ---- stage full-K A tile, swizzled: LDS[row][g] = global[row][g^(row&7)]
    {
        const int srow = lane >> 5;          // 0..1 (row within 1KB instr)
        const int sg   = lane & 31;          // 16B group within row
        #pragma unroll
        for (int p = 0; p < 16; ++p) {
            const int pp = wave * 16 + p;    // wave-uniform instr index 0..63
            const int row = pp * 2 + srow;
            const __hip_bfloat16* ga =
                X + (size_t)(i * BM + row) * DIM + ((sg ^ (row & 7)) << 3);
            __builtin_amdgcn_global_load_lds(
                (const __attribute__((address_space(1))) void*)ga,
                (__attribute__((address_space(3))) void*)(As + pp * 512),
                16, 0, 0);
        }
    }
    __syncthreads();   // the ONLY barrier

    float rowacc[4][4] = {};
    const int lmask = lm & 7;

    for (int j = j0; j < j1; ++j) {
        // per-fc lane base pointers into B tile j
        const __hip_bfloat16* bp[4];
        #pragma unroll
        for (int fc = 0; fc < 4; ++fc)
            bp[fc] = Y + (size_t)(j * BM + wc * 64 + fc * 16 + lm) * DIM + lq * 8;

        f32x4 acc[4][4] = {};

        bf16x8 ac[4], bc[4], an_[4], bn_[4];
        #pragma unroll
        for (int f = 0; f < 4; ++f) {
            const int ra = wr * 64 + f * 16 + lm;
            ac[f] = *(const bf16x8*)(As + ra * DIM + ((lq ^ lmask) << 3));
            bc[f] = *(const bf16x8*)(bp[f]);
        }
        #pragma unroll
        for (int s = 0; s < 8; ++s) {
            if (s < 7) {
                #pragma unroll
                for (int f = 0; f < 4; ++f) {
                    const int ra = wr * 64 + f * 16 + lm;
                    an_[f] = *(const bf16x8*)(As + ra * DIM +
                                              ((((s + 1) * 4 + lq) ^ lmask) << 3));
                    bn_[f] = *(const bf16x8*)(bp[f] + (s + 1) * 32);
                }
            }
            #pragma unroll
            for (int fr = 0; fr < 4; ++fr)
                #pragma unroll
                for (int fc = 0; fc < 4; ++fc)
                    acc[fr][fc] = __builtin_amdgcn_mfma_f32_16x16x32_bf16(
                        ac[fr], bc[fc], acc[fr][fc], 0, 0, 0);
            if (s < 7) {
                #pragma unroll
                for (int f = 0; f < 4; ++f) { ac[f] = an_[f]; bc[f] = bn_[f]; }
            }
        }

        // ---- per-tile epilogue: exp, col sums; rows accumulate in regs ----
        const bool docol = (!sym) || (j > i);
        #pragma unroll
        for (int fc = 0; fc < 4; ++fc) {
            float cs = 0.0f;
            #pragma unroll
            for (int fr = 0; fr < 4; ++fr)
                #pragma unroll
                for (int r = 0; r < 4; ++r) {
                    const float e = __expf(acc[fr][fc][r] * TAU_INV);
                    rowacc[fr][r] += e;
                    cs += e;
                }
            if (docol) {
                cs += __shfl_xor(cs, 16, 64);
                cs += __shfl_xor(cs, 32, 64);
                if (lq == 0)
                    atomicAdd(&Scol[j * BM + wc * 64 + fc * 16 + lm], cs);
            }
        }
    }

    // ---- row sums: once per block ----
    #pragma unroll
    for (int fr = 0; fr < 4; ++fr)
        #pragma unroll
        for (int r = 0; r < 4; ++r) {
            float s = rowacc[fr][r];
            s += __shfl_xor(s, 1, 64);
            s += __shfl_xor(s, 2, 64);
            s += __shfl_xor(s, 4, 64);
            s += __shfl_xor(s, 8, 64);
            if (lm == 0)
                atomicAdd(&Srow[i * BM + wr * 64 + fr * 16 + lq * 4 + r], s);
        }
}

// ---------------------------------------------------------------------------
// Kernel 3: per-row loss + mean reduction.
// ---------------------------------------------------------------------------
__global__ __launch_bounds__(256) void loss_kernel(
    const float* __restrict__ S_aa, const float* __restrict__ S_abr,
    const float* __restrict__ S_abc, const float* __restrict__ S_bb,
    const float* __restrict__ d_aa, const float* __restrict__ d_bb,
    const float* __restrict__ pos, float* __restrict__ out)
{
    const int i = blockIdx.x * 256 + threadIdx.x;
    const float den1 = S_aa[i] + S_abr[i] - expf(TAU_INV * d_aa[i]);
    const float den2 = S_bb[i] + S_abc[i] - expf(TAU_INV * d_bb[i]);
    float v = 0.5f * (logf(den1) + logf(den2)) - TAU_INV * pos[i];

    __shared__ float red[4];
    #pragma unroll
    for (int m = 1; m < 64; m <<= 1) v += __shfl_xor(v, m, 64);
    if ((threadIdx.x & 63) == 0) red[threadIdx.x >> 6] = v;
    __syncthreads();
    if (threadIdx.x == 0)
        atomicAdd(out, (red[0] + red[1] + red[2] + red[3]) * (1.0f / N_ROWS));
}

// ---------------------------------------------------------------------------
extern "C" void kernel_launch(void* const* d_in, const int* in_sizes, int n_in,
                              void* d_out, int out_size, void* d_ws, size_t ws_size,
                              hipStream_t stream)
{
    const float* z1 = (const float*)d_in[0];
    const float* z2 = (const float*)d_in[1];
    float* out = (float*)d_out;

    char* ws = (char*)d_ws;
    __hip_bfloat16* An = (__hip_bfloat16*)ws;                        // 4 MB
    __hip_bfloat16* Bn = (__hip_bfloat16*)(ws + 4194304);            // 4 MB
    float* S_aa  = (float*)(ws + 8388608);
    float* S_abr = S_aa  + N_ROWS;
    float* S_abc = S_abr + N_ROWS;
    float* S_bb  = S_abc + N_ROWS;
    float* d_aa  = S_bb  + N_ROWS;
    float* d_bb  = d_aa  + N_ROWS;
    float* pos   = d_bb  + N_ROWS;

    hipMemsetAsync(out, 0, sizeof(float), stream);

    // normalize also zeroes S_aa..S_bb (4*N_ROWS floats starting at S_aa)
    normalize_kernel<<<N_ROWS, 256, 0, stream>>>(z1, z2, An, Bn,
                                                 d_aa, d_bb, pos, S_aa);

    dim3 grid(NTILE / JCHUNK, NTILE, 3);   // (8, 64, 3); z: 0=AB, 1=AA, 2=BB
    gram_kernel<<<grid, 256, 0, stream>>>(An, Bn, S_aa, S_bb, S_abr, S_abc);

    loss_kernel<<<N_ROWS / 256, 256, 0, stream>>>(S_aa, S_abr, S_abc, S_bb,
                                                  d_aa, d_bb, pos, out);
}

// Round 4
// 203.856 us; speedup vs baseline: 1.5354x; 1.5354x over previous
//
#include <hip/hip_runtime.h>
#include <hip/hip_bf16.h>

#define N_ROWS 8192
#define NZ 16384           // rows of Z = [An; Bn]
#define DIM 256
#define TAU_INV 2.0f
#define BR 128             // block tile rows
#define BC 256             // block tile cols
#define BK 64

typedef float f32x4 __attribute__((ext_vector_type(4)));
typedef short bf16x8 __attribute__((ext_vector_type(8)));

// ---------------------------------------------------------------------------
// Kernel 1: one WAVE per row. L2-normalize z1,z2 rows -> bf16 Zn (An rows
// 0..8191, Bn rows 8192..16383); pos[i] = dot of the QUANTIZED an_i,bn_i.
// Also zeroes the S accumulator (16384 floats).
// ---------------------------------------------------------------------------
__global__ __launch_bounds__(256) void normalize_kernel(
    const float* __restrict__ z1, const float* __restrict__ z2,
    __hip_bfloat16* __restrict__ Zn, float* __restrict__ pos,
    float* __restrict__ Szero)
{
    const int tid = threadIdx.x;
    if (blockIdx.x < 64) Szero[blockIdx.x * 256 + tid] = 0.0f;  // 64*256=16384

    const int wave = tid >> 6;
    const int lane = tid & 63;
    const int row = blockIdx.x * 4 + wave;      // 0..8191

    const float4 a = ((const float4*)(z1 + (size_t)row * DIM))[lane];
    const float4 b = ((const float4*)(z2 + (size_t)row * DIM))[lane];

    auto wsum = [&](float v) -> float {
        #pragma unroll
        for (int m = 1; m < 64; m <<= 1) v += __shfl_xor(v, m, 64);
        return v;
    };

    const float na2 = wsum(a.x*a.x + a.y*a.y + a.z*a.z + a.w*a.w);
    const float nb2 = wsum(b.x*b.x + b.y*b.y + b.z*b.z + b.w*b.w);
    const float ia = 1.0f / sqrtf(na2);   // norms ~16; eps never binds
    const float ib = 1.0f / sqrtf(nb2);

    __hip_bfloat16 ah[4] = { __float2bfloat16(a.x*ia), __float2bfloat16(a.y*ia),
                             __float2bfloat16(a.z*ia), __float2bfloat16(a.w*ia) };
    __hip_bfloat16 bh[4] = { __float2bfloat16(b.x*ib), __float2bfloat16(b.y*ib),
                             __float2bfloat16(b.z*ib), __float2bfloat16(b.w*ib) };
    *(ushort4*)(Zn + (size_t)row * DIM + lane * 4) = *(ushort4*)ah;
    *(ushort4*)(Zn + (size_t)(N_ROWS + row) * DIM + lane * 4) = *(ushort4*)bh;

    float qd = 0.0f;
    #pragma unroll
    for (int k = 0; k < 4; ++k)
        qd += __bfloat162float(ah[k]) * __bfloat162float(bh[k]);
    qd = wsum(qd);
    if (lane == 0) pos[row] = qd;
}

// ---------------------------------------------------------------------------
// Kernel 2: symmetric gram of Z (16384x256). Block tile 128(rows)x256(cols),
// wave tile 64x128 (4x8 frags of 16x16x32 bf16). Upper triangle only:
// process (ti,tj) iff tj >= ti/2; diagonal-crossing blocks mask gj<=gi after
// exp. Row sums AND col sums (by symmetry, colsum feeds S too) -> one S.
// LDS 16B-group XOR swizzle (R1->R2 fix, measured 0 conflicts).
// ---------------------------------------------------------------------------
__global__ __launch_bounds__(256, 2) void gram_kernel(
    const __hip_bfloat16* __restrict__ Z, float* __restrict__ S)
{
    const int tj = blockIdx.x;          // col tile (256 cols), 0..63
    const int ti = blockIdx.y;          // row tile (128 rows), 0..127
    if (tj < (ti >> 1)) return;
    const bool diag = (tj == (ti >> 1));

    __shared__ __hip_bfloat16 As[BR * BK];   // 16 KB
    __shared__ __hip_bfloat16 Bs[BC * BK];   // 32 KB

    const int tid  = threadIdx.x;
    const int wave = tid >> 6;
    const int lane = tid & 63;
    const int wr = wave >> 1;           // row half (0..1) -> 64 rows
    const int wc = wave & 1;            // col half (0..1) -> 128 cols
    const int lm = lane & 15;
    const int lq = lane >> 4;

    const int rowBase = ti * BR;
    const int colBase = tj * BC;

    // staging lane geometry: chunk = 8 rows x 8 groups of 16B (1 KB)
    const int srow  = lane >> 3;                // 0..7
    const int sgcol = ((lane & 7) ^ srow) << 3; // swizzled elem offset in row

    f32x4 acc[4][8] = {};

    for (int k0 = 0; k0 < DIM; k0 += BK) {
        #pragma unroll
        for (int c = 0; c < 4; ++c) {           // A: 16 chunks, 4 per wave
            const int ch = wave * 4 + c;
            const int r = ch * 8 + srow;
            const __hip_bfloat16* ga = Z + (size_t)(rowBase + r) * DIM + k0 + sgcol;
            __builtin_amdgcn_global_load_lds(
                (const __attribute__((address_space(1))) void*)ga,
                (__attribute__((address_space(3))) void*)(As + ch * 512),
                16, 0, 0);
        }
        #pragma unroll
        for (int c = 0; c < 8; ++c) {           // B: 32 chunks, 8 per wave
            const int ch = wave * 8 + c;
            const int r = ch * 8 + srow;
            const __hip_bfloat16* gb = Z + (size_t)(colBase + r) * DIM + k0 + sgcol;
            __builtin_amdgcn_global_load_lds(
                (const __attribute__((address_space(1))) void*)gb,
                (__attribute__((address_space(3))) void*)(Bs + ch * 512),
                16, 0, 0);
        }
        __syncthreads();

        #pragma unroll
        for (int kk = 0; kk < BK; kk += 32) {
            const int g = (kk >> 3) + lq;       // 16B group index 0..7
            bf16x8 af[4], bfr[8];
            #pragma unroll
            for (int f = 0; f < 4; ++f) {
                const int ra = wr * 64 + f * 16 + lm;
                af[f] = *(const bf16x8*)(As + ra * BK + ((g ^ (ra & 7)) << 3));
            }
            #pragma unroll
            for (int f = 0; f < 8; ++f) {
                const int rb = wc * 128 + f * 16 + lm;
                bfr[f] = *(const bf16x8*)(Bs + rb * BK + ((g ^ (rb & 7)) << 3));
            }
            #pragma unroll
            for (int fr = 0; fr < 4; ++fr)
                #pragma unroll
                for (int fc = 0; fc < 8; ++fc)
                    acc[fr][fc] = __builtin_amdgcn_mfma_f32_16x16x32_bf16(
                        af[fr], bfr[fc], acc[fr][fc], 0, 0, 0);
        }
        __syncthreads();
    }

    // ---- epilogue ----
    // C/D layout (m89/m91): col = lane&15, row = (lane>>4)*4 + reg
    #pragma unroll
    for (int fr = 0; fr < 4; ++fr)
        #pragma unroll
        for (int fc = 0; fc < 8; ++fc)
            #pragma unroll
            for (int r = 0; r < 4; ++r)
                acc[fr][fc][r] = __expf(acc[fr][fc][r] * TAU_INV);

    if (diag) {   // zero at-or-below-diagonal elements (pairs counted once)
        #pragma unroll
        for (int fr = 0; fr < 4; ++fr) {
            const int gi = rowBase + wr * 64 + fr * 16 + lq * 4;
            #pragma unroll
            for (int fc = 0; fc < 8; ++fc) {
                const int gj = colBase + wc * 128 + fc * 16 + lm;
                #pragma unroll
                for (int r = 0; r < 4; ++r)
                    if (gj <= gi + r) acc[fr][fc][r] = 0.0f;
            }
        }
    }

    // wave partials -> LDS scratch (all waves are past the last barrier)
    float* rowsc = (float*)As;          // [2 (wc)][128]
    float* colsc = rowsc + 256;         // [2 (wr)][256]

    #pragma unroll
    for (int fr = 0; fr < 4; ++fr)
        #pragma unroll
        for (int r = 0; r < 4; ++r) {
            float s = 0.0f;
            #pragma unroll
            for (int fc = 0; fc < 8; ++fc) s += acc[fr][fc][r];
            s += __shfl_xor(s, 1, 64);
            s += __shfl_xor(s, 2, 64);
            s += __shfl_xor(s, 4, 64);
            s += __shfl_xor(s, 8, 64);
            if (lm == 0)
                rowsc[wc * 128 + wr * 64 + fr * 16 + lq * 4 + r] = s;
        }
    #pragma unroll
    for (int fc = 0; fc < 8; ++fc) {
        float s = 0.0f;
        #pragma unroll
        for (int fr = 0; fr < 4; ++fr)
            #pragma unroll
            for (int r = 0; r < 4; ++r) s += acc[fr][fc][r];
        s += __shfl_xor(s, 16, 64);
        s += __shfl_xor(s, 32, 64);
        if (lq == 0)
            colsc[wr * 256 + wc * 128 + fc * 16 + lm] = s;
    }
    __syncthreads();

    if (tid < 128)
        atomicAdd(&S[rowBase + tid], rowsc[tid] + rowsc[128 + tid]);
    atomicAdd(&S[colBase + tid], colsc[tid] + colsc[256 + tid]);
}

// ---------------------------------------------------------------------------
// Kernel 3: per-row loss + mean. S[i] already excludes the diagonal, so
// den1 = S[i], den2 = S[N+i] directly.
// ---------------------------------------------------------------------------
__global__ __launch_bounds__(256) void loss_kernel(
    const float* __restrict__ S, const float* __restrict__ pos,
    float* __restrict__ out)
{
    const int i = blockIdx.x * 256 + threadIdx.x;
    float v = 0.5f * (logf(S[i]) + logf(S[N_ROWS + i])) - TAU_INV * pos[i];

    __shared__ float red[4];
    #pragma unroll
    for (int m = 1; m < 64; m <<= 1) v += __shfl_xor(v, m, 64);
    if ((threadIdx.x & 63) == 0) red[threadIdx.x >> 6] = v;
    __syncthreads();
    if (threadIdx.x == 0)
        atomicAdd(out, (red[0] + red[1] + red[2] + red[3]) * (1.0f / N_ROWS));
}

// ---------------------------------------------------------------------------
extern "C" void kernel_launch(void* const* d_in, const int* in_sizes, int n_in,
                              void* d_out, int out_size, void* d_ws, size_t ws_size,
                              hipStream_t stream)
{
    const float* z1 = (const float*)d_in[0];
    const float* z2 = (const float*)d_in[1];
    float* out = (float*)d_out;

    char* ws = (char*)d_ws;
    __hip_bfloat16* Zn = (__hip_bfloat16*)ws;            // 16384*256*2 = 8 MB
    float* S   = (float*)(ws + 8388608);                 // 16384 floats
    float* pos = S + NZ;                                 // 8192 floats

    hipMemsetAsync(out, 0, sizeof(float), stream);

    // normalize also zeroes S
    normalize_kernel<<<N_ROWS / 4, 256, 0, stream>>>(z1, z2, Zn, pos, S);

    dim3 grid(NZ / BC, NZ / BR);    // (64, 128); upper triangle via early-exit
    gram_kernel<<<grid, 256, 0, stream>>>(Zn, S);

    loss_kernel<<<N_ROWS / 256, 256, 0, stream>>>(S, pos, out);
}